// Round 11
// baseline (385.650 us; speedup 1.0000x reference)
//
#include <hip/hip_runtime.h>

// CSTR gated-estimator trajectory cost — 1 lane/sample, linear-t expansion.
// B=8192 samples, T=2048 sequential RK4 steps, N=2 states.
//
// Model (fit R0/R1/R8/R10): wall/step = max(chain, issue);
//   chain = 6.5*deps + ~52*trans; issue ~ hidden until it meets chain.
// R10 = 193 cyc: chain d->...->phi = 13 deps + 2 trans. This version uses
// t-vector linearity: z' = z0 + d*v  =>  t(z') = t0 + d*(U v), with
//   z0 = (q1,q2,h1,h2), v = (g,g,dx1,dx2) computable BEFORE d.
// Post-d chain: {x',t'} (1 fma) -> mul -> fma -> add(phi) -> exp2 -> add
// -> rcp  = 4 deps + 2 trans ~ 136 cyc. Pre-d block (~28 ops: q,g,t0,uv)
// issues under the trans latency. No DPP (R7's poison), no packing (R8 wash).
//
// Math (same liberties as all passing rounds):
//   RK4 collapsed: x_i' = .98 x_i + .01 x_oth + Hs*u + C_i + w_i, u = K.h'
//   h' = h + d*(x-h);  d = rcp(1 + exp2(phi_s)), phi_s pre-scaled by -log2(e)
//   Hs*u = kxh + d*g, g = Hs*K.(x-h); kxhC (=kxh+C1) kept incrementally:
//   kxhC' = fma(d,g,kxhC)  (exact).
//   Step 0: phi=-inf -> E=0 -> d=rcp(1)=1 exact (gate forced open).
//   Cost moments {Sx1^2,Sx2^2,Sx1x2,Sd}; Sum us^2 reconstructed at end.

#define T_STEPS 2048
#define BATCH   8192

__global__ __launch_bounds__(64, 1) void cstr_kernel(
    const float* __restrict__ w,   // (B, 2, T)
    const float* __restrict__ K,   // (1, 2)
    const float* __restrict__ L,   // (4, 4)
    const float* __restrict__ M,   // (1, 4)
    const float* __restrict__ Mo,  // (1, 1)
    float* __restrict__ out)       // (B,)
{
    const int s = blockIdx.x * 64 + (int)threadIdx.x;

    constexpr float Hs = 0.01f;
    constexpr float Ad = 1.0f - 2.0f * Hs;          // 0.98
    constexpr float Rc = 0.1f;
    constexpr float SC = -1.44269504088896340736f;  // -log2(e)

    const float k1 = K[0], k2 = K[1];

    // upper-tri fold of L, pre-scaled into exp2 domain
    const float u11 = L[0] * SC;
    const float u12 = (L[1] + L[4]) * SC;
    const float u13 = (L[2] + L[8]) * SC;
    const float u14 = (L[3] + L[12]) * SC;
    const float u22 = L[5] * SC;
    const float u23 = (L[6] + L[9]) * SC;
    const float u24 = (L[7] + L[13]) * SC;
    const float u33 = L[10] * SC;
    const float u34 = (L[11] + L[14]) * SC;
    const float u44 = L[15] * SC;
    const float u1112 = u11 + u12;
    const float m1s = M[0] * SC, m2s = M[1] * SC, m3s = M[2] * SC, m4s = M[3] * SC;
    const float c0s = Mo[0] * SC;

    const float hk1 = Hs * k1, hk2 = Hs * k2;
    const float C1v = 0.5f * Hs * Hs;               // +H^2/2
    const float C21 = -1.5f * Hs * Hs;              // C2 - C1

    // ---- state ----
    float x1 = 1.0f, x2 = 0.0f;   // x0 = (1, 0)
    float h1 = x1, h2 = x2;
    float dx1 = 0.0f, dx2 = 0.0f;
    float kxhC = hk1 + C1v;       // Hs*K.h + C1 (h0=(1,0) -> K.h0 = k1)
    float phi = __int_as_float(0xff800000u);  // -inf: step 0 -> E=0 -> d=1
    float aA1 = 0.0f, aA2 = 0.0f; // Sum x1^2, Sum x2^2
    float aXY = 0.0f;             // Sum x1*x2
    float aD  = 0.0f;             // Sum delta

    auto step = [&](float w1, float w2, bool cost) {
        float E = __builtin_amdgcn_exp2f(phi);       // exp(-phi_full)

        // ---- pre-d block: fills the exp/rcp latency ----
        float g   = fmaf(hk1, dx1, hk2 * dx2);       // Hs*K.(x-h)
        float b1  = w1 + kxhC;                       // w1 + C1 + Hs*K.h
        float w2c = w2 + C21;
        float b2  = w2c + kxhC;                      // w2 + C2 + Hs*K.h
        float q1  = fmaf(Ad, x1, fmaf(Hs, x2, b1));
        float q2  = fmaf(Ad, x2, fmaf(Hs, x1, b2));
        // t0 = U z0 + m, z0 = (q1,q2,h1,h2) (upper-tri half-form)
        float t01 = fmaf(u11, q1, m1s);
        t01 = fmaf(u12, q2, t01);
        t01 = fmaf(u13, h1, t01);
        t01 = fmaf(u14, h2, t01);
        float t02 = fmaf(u22, q2, m2s);
        t02 = fmaf(u23, h1, t02);
        t02 = fmaf(u24, h2, t02);
        float t03 = fmaf(u33, h1, m3s);
        t03 = fmaf(u34, h2, t03);
        float t04 = fmaf(u44, h2, m4s);
        // uv = U v, v = (g, g, dx1, dx2)
        float uv1 = fmaf(u1112, g, fmaf(u13, dx1, u14 * dx2));
        float uv2 = fmaf(u22, g, fmaf(u23, dx1, u24 * dx2));
        float uv3 = fmaf(u33, dx1, u34 * dx2);
        float uv4 = u44 * dx2;

        float d = __builtin_amdgcn_rcpf(1.0f + E);   // sigmoid(phi)

        if (cost) {                 // stage cost uses PRE-update x, this d
            aA1 = fmaf(x1, x1, aA1);
            aA2 = fmaf(x2, x2, aA2);
            aXY = fmaf(x1, x2, aXY);
            aD += d;
        }
        // ---- post-d: 4-dep chain to phi ----
        float nx1 = fmaf(d, g, q1);
        float nx2 = fmaf(d, g, q2);
        float nh1 = fmaf(d, dx1, h1);
        float nh2 = fmaf(d, dx2, h2);
        float nt1 = fmaf(d, uv1, t01);
        float nt2 = fmaf(d, uv2, t02);
        float nt3 = fmaf(d, uv3, t03);
        float nt4 = fmaf(d, uv4, t04);
        float ma = nx2 * nt2;
        float mb = fmaf(nh2, nt4, c0s);
        float pa = fmaf(nx1, nt1, ma);
        float pb = fmaf(nh1, nt3, mb);
        phi = pa + pb;                               // phi(z') + c0, exp2 domain
        kxhC = fmaf(d, g, kxhC);                     // exact incremental
        x1 = nx1; x2 = nx2; h1 = nh1; h2 = nh2;
        dx1 = x1 - h1;
        dx2 = x2 - h2;
    };

    // 8-step chunks (2 float4 per stream), double-buffered
    auto chunk = [&](const float4* b0, const float4* b1, bool lastc) {
        #pragma unroll
        for (int q = 0; q < 2; ++q) {
            float4 a = b0[q];
            float4 b = b1[q];
            step(a.x, b.x, true);
            step(a.y, b.y, true);
            step(a.z, b.z, true);
            step(a.w, b.w, !(lastc && (q == 1)));    // t=T-1: no stage cost
        }
    };

    const float4* r0 = reinterpret_cast<const float4*>(w + (size_t)s * 2 * T_STEPS);
    const float4* r1 = reinterpret_cast<const float4*>(w + (size_t)s * 2 * T_STEPS + T_STEPS);

    float4 A0[2], A1[2], B0[2], B1[2];
    #pragma unroll
    for (int q = 0; q < 2; ++q) { A0[q] = r0[q];     A1[q] = r1[q]; }
    #pragma unroll
    for (int q = 0; q < 2; ++q) { B0[q] = r0[2 + q]; B1[q] = r1[2 + q]; }

    chunk(A0, A1, false);                            // chunk 0

    for (int i = 0; i < 127; ++i) {                  // chunks 1..254
        const float4* p0 = r0 + (size_t)(2 + 2 * i) * 2;
        const float4* p1 = r1 + (size_t)(2 + 2 * i) * 2;
        #pragma unroll
        for (int q = 0; q < 2; ++q) { A0[q] = p0[q]; A1[q] = p1[q]; }
        chunk(B0, B1, false);                        // chunk 1+2i
        const float4* q0 = r0 + (size_t)(3 + 2 * i) * 2;
        const float4* q1 = r1 + (size_t)(3 + 2 * i) * 2;
        #pragma unroll
        for (int q = 0; q < 2; ++q) { B0[q] = q0[q]; B1[q] = q1[q]; }
        chunk(A0, A1, false);                        // chunk 2+2i
    }
    chunk(B0, B1, true);                             // chunk 255 (last: no cost)

    // Sum us^2 = k1^2 Sx1^2 + k2^2 Sx2^2 + 2 k1 k2 Sx1x2
    float us2 = fmaf(k1 * k1, aA1, fmaf(k2 * k2, aA2, 2.0f * k1 * k2 * aXY));
    float J = aA1 + aA2 + Rc * us2 + aD
            + 10.0f * fmaf(x1, x1, x2 * x2);         // terminal cost
    out[s] = J;
}

extern "C" void kernel_launch(void* const* d_in, const int* in_sizes, int n_in,
                              void* d_out, int out_size, void* d_ws, size_t ws_size,
                              hipStream_t stream) {
    const float* w  = (const float*)d_in[0];
    const float* K  = (const float*)d_in[1];
    const float* L  = (const float*)d_in[2];
    const float* M  = (const float*)d_in[3];
    const float* Mo = (const float*)d_in[4];
    float* out = (float*)d_out;

    // 8192 samples, 1 lane each = 128 blocks of 64 (1 wave/block)
    hipLaunchKernelGGL(cstr_kernel, dim3(BATCH / 64), dim3(64), 0, stream,
                       w, K, L, M, Mo, out);
}